// Round 1
// baseline (1205.044 us; speedup 1.0000x reference)
//
#include <hip/hip_runtime.h>

#define EPS 1e-5f

typedef __attribute__((ext_vector_type(8))) short bf16x8;
typedef __attribute__((ext_vector_type(4))) float f32x4;

__device__ __forceinline__ unsigned short f2bf(float f) {
  union { float f; unsigned u; } c; c.f = f;
  unsigned u = c.u;
  u += 0x7FFFu + ((u >> 16) & 1u);   // round-to-nearest-even
  return (unsigned short)(u >> 16);
}
__device__ __forceinline__ float bf2f(unsigned short h) {
  union { unsigned u; float f; } c; c.u = (unsigned)h << 16;
  return c.f;
}
__device__ __forceinline__ void cvt4(const float4 f, unsigned short* dst) {
  ushort4 o; o.x = f2bf(f.x); o.y = f2bf(f.y); o.z = f2bf(f.z); o.w = f2bf(f.w);
  *reinterpret_cast<ushort4*>(dst) = o;
}

// ---------------------------------------------------------------------------
// K1: h = relu(bn1(conv1(x)))   per batch GEMM M=128, N=4096, K=512
// tiles: BM=128, BN=64, BK=64; 4 waves (2x2), wave tile 64x32
// LDS tiles k-major with +8 pad (row pitch 144B: 16B-aligned, conflict-light)
// ---------------------------------------------------------------------------
__global__ __launch_bounds__(256) void k1_conv1(
    const float* __restrict__ x, const float* __restrict__ w1,
    const float* __restrict__ g1, const float* __restrict__ b1,
    const float* __restrict__ m1, const float* __restrict__ v1,
    unsigned short* __restrict__ h) {
  __shared__ unsigned short As[128 * 72];
  __shared__ unsigned short Bs[64 * 72];
  __shared__ float sc[128], bi[128];
  const int t = threadIdx.x;
  const int b = blockIdx.y;
  const int n0 = blockIdx.x * 64;
  if (t < 128) {
    float s = g1[t] * rsqrtf(v1[t] + EPS);
    sc[t] = s; bi[t] = b1[t] - m1[t] * s;
  }
  const int lane = t & 63, wv = t >> 6;
  const int wm = (wv >> 1) * 64, wn = (wv & 1) * 32;
  const int l15 = lane & 15, kg = lane >> 4;
  f32x4 acc[4][2] = {};
  const float* xb = x + (size_t)b * 512 * 4096;
  for (int kt = 0; kt < 512; kt += 64) {
    __syncthreads();
    { // stage A = w1 tile (row-major, k-contiguous): 32 k per thread
      const int row = t >> 1, kh = (t & 1) * 32;
      const float* src = w1 + row * 512 + kt + kh;
      unsigned short* dst = As + row * 72 + kh;
      #pragma unroll
      for (int i = 0; i < 8; i++)
        cvt4(reinterpret_cast<const float4*>(src)[i], dst + 4 * i);
    }
    { // stage B^T = x tile transposed: [pixel][channel]
      const int c = t >> 2, p0 = (t & 3) * 16;
      const float* src = xb + (size_t)(kt + c) * 4096 + n0 + p0;
      #pragma unroll
      for (int i = 0; i < 4; i++) {
        float4 f = reinterpret_cast<const float4*>(src)[i];
        const int p = p0 + 4 * i;
        Bs[(p + 0) * 72 + c] = f2bf(f.x);
        Bs[(p + 1) * 72 + c] = f2bf(f.y);
        Bs[(p + 2) * 72 + c] = f2bf(f.z);
        Bs[(p + 3) * 72 + c] = f2bf(f.w);
      }
    }
    __syncthreads();
    #pragma unroll
    for (int kk = 0; kk < 64; kk += 32) {
      bf16x8 bfr[2];
      #pragma unroll
      for (int nf = 0; nf < 2; nf++)
        bfr[nf] = *reinterpret_cast<const bf16x8*>(
            &Bs[(wn + nf * 16 + l15) * 72 + kk + 8 * kg]);
      #pragma unroll
      for (int mf = 0; mf < 4; mf++) {
        bf16x8 af = *reinterpret_cast<const bf16x8*>(
            &As[(wm + mf * 16 + l15) * 72 + kk + 8 * kg]);
        #pragma unroll
        for (int nf = 0; nf < 2; nf++)
          acc[mf][nf] = __builtin_amdgcn_mfma_f32_16x16x32_bf16(
              af, bfr[nf], acc[mf][nf], 0, 0, 0);
      }
    }
  }
  unsigned short* hb = h + (size_t)b * 128 * 4096;
  #pragma unroll
  for (int mf = 0; mf < 4; mf++)
    #pragma unroll
    for (int nf = 0; nf < 2; nf++) {
      const int px = n0 + wn + nf * 16 + l15;
      #pragma unroll
      for (int r = 0; r < 4; r++) {
        const int ch = wm + mf * 16 + 4 * kg + r;   // C/D: row = 4*kg + reg
        float val = fmaxf(fmaf(acc[mf][nf][r], sc[ch], bi[ch]), 0.f);
        hb[(size_t)ch * 4096 + px] = f2bf(val);
      }
    }
}

// ---------------------------------------------------------------------------
// K2: qkv = Wqkv * h ; epilogue: bn(q), softmax16(k), bn(v)
// M=112 (64 q | 16 k | 32 v), K=128, BN=64; 4 waves, each wave = 16 px x 112
// ---------------------------------------------------------------------------
__global__ __launch_bounds__(256) void k2_qkv(
    const unsigned short* __restrict__ h,
    const float* __restrict__ qw, const float* __restrict__ kw,
    const float* __restrict__ vw,
    const float* __restrict__ gq, const float* __restrict__ bq,
    const float* __restrict__ mq, const float* __restrict__ vq,
    const float* __restrict__ gv, const float* __restrict__ bv,
    const float* __restrict__ mv, const float* __restrict__ vv,
    unsigned short* __restrict__ qo, unsigned short* __restrict__ ko,
    unsigned short* __restrict__ vo) {
  __shared__ unsigned short As[112 * 72];
  __shared__ unsigned short Bs[64 * 72];
  __shared__ float sc[112], bi[112];
  const int t = threadIdx.x, b = blockIdx.y, n0 = blockIdx.x * 64;
  if (t < 112) {
    float s, bb;
    if (t < 64)      { s = gq[t] * rsqrtf(vq[t] + EPS); bb = bq[t] - mq[t] * s; }
    else if (t < 80) { s = 1.f; bb = 0.f; }               // k: no BN
    else { int c = t - 80; s = gv[c] * rsqrtf(vv[c] + EPS); bb = bv[c] - mv[c] * s; }
    sc[t] = s; bi[t] = bb;
  }
  const int lane = t & 63, wv = t >> 6;
  const int l15 = lane & 15, kg = lane >> 4;
  f32x4 acc[7] = {};
  const unsigned short* hb = h + (size_t)b * 128 * 4096;
  for (int kt = 0; kt < 128; kt += 64) {
    __syncthreads();
    for (int e = t; e < 112 * 64; e += 256) {  // stage A (3 weight sources)
      const int row = e >> 6, kk2 = e & 63, gk = kt + kk2;
      float val = row < 64 ? qw[row * 128 + gk]
                : row < 80 ? kw[(row - 64) * 128 + gk]
                           : vw[(row - 80) * 128 + gk];
      As[row * 72 + kk2] = f2bf(val);
    }
    { // stage B^T from h (bf16 already)
      const int c = t >> 2, p0 = (t & 3) * 16;
      const unsigned short* src = hb + (size_t)(kt + c) * 4096 + n0 + p0;
      #pragma unroll
      for (int i = 0; i < 4; i++) {
        ushort4 u = reinterpret_cast<const ushort4*>(src)[i];
        const int p = p0 + 4 * i;
        Bs[(p + 0) * 72 + c] = u.x; Bs[(p + 1) * 72 + c] = u.y;
        Bs[(p + 2) * 72 + c] = u.z; Bs[(p + 3) * 72 + c] = u.w;
      }
    }
    __syncthreads();
    #pragma unroll
    for (int kk = 0; kk < 64; kk += 32) {
      bf16x8 bfr = *reinterpret_cast<const bf16x8*>(
          &Bs[(wv * 16 + l15) * 72 + kk + 8 * kg]);
      #pragma unroll
      for (int mf = 0; mf < 7; mf++) {
        bf16x8 af = *reinterpret_cast<const bf16x8*>(
            &As[(mf * 16 + l15) * 72 + kk + 8 * kg]);
        acc[mf] = __builtin_amdgcn_mfma_f32_16x16x32_bf16(af, bfr, acc[mf], 0, 0, 0);
      }
    }
  }
  const int px = n0 + wv * 16 + l15;
  // softmax over the 16 k-channels (frag 4): regs + shfl over kg groups
  float e0[4];
  float mx = -1e30f;
  #pragma unroll
  for (int r = 0; r < 4; r++) mx = fmaxf(mx, acc[4][r]);
  mx = fmaxf(mx, __shfl_xor(mx, 16));
  mx = fmaxf(mx, __shfl_xor(mx, 32));
  float s = 0.f;
  #pragma unroll
  for (int r = 0; r < 4; r++) { e0[r] = expf(acc[4][r] - mx); s += e0[r]; }
  s += __shfl_xor(s, 16); s += __shfl_xor(s, 32);
  const float inv = 1.f / s;
  #pragma unroll
  for (int mf = 0; mf < 7; mf++) {
    #pragma unroll
    for (int r = 0; r < 4; r++) {
      const int row = mf * 16 + 4 * kg + r;
      if (mf == 4) {
        ko[((size_t)b * 16 + (row - 64)) * 4096 + px] = f2bf(e0[r] * inv);
      } else {
        float val = fmaf(acc[mf][r], sc[row], bi[row]);
        if (row < 64) qo[((size_t)b * 64 + row) * 4096 + px] = f2bf(val);
        else          vo[((size_t)b * 32 + (row - 80)) * 4096 + px] = f2bf(val);
      }
    }
  }
}

// ---------------------------------------------------------------------------
// K3: content_lambda[b][kc][vc] = sum_px k[kc][px]*v[vc][px]   (fp32 accum)
// one block per batch; thread = (kc = t>>4, pl = t&15)
// ---------------------------------------------------------------------------
__global__ __launch_bounds__(256) void k3_lambda(
    const unsigned short* __restrict__ ko, const unsigned short* __restrict__ vo,
    float* __restrict__ lc) {
  const int t = threadIdx.x, b = blockIdx.x;
  const int kc = t >> 4, pl = t & 15;
  const unsigned short* kb = ko + ((size_t)b * 16 + kc) * 4096;
  const unsigned short* vb = vo + (size_t)b * 32 * 4096;
  float acc[32] = {};
  for (int i = 0; i < 256; i++) {
    const int pix = pl + 16 * i;
    const float kv = bf2f(kb[pix]);
    #pragma unroll
    for (int vc = 0; vc < 32; vc++)
      acc[vc] = fmaf(kv, bf2f(vb[vc * 4096 + pix]), acc[vc]);
  }
  #pragma unroll
  for (int vc = 0; vc < 32; vc++) {
    float a = acc[vc];
    a += __shfl_xor(a, 1); a += __shfl_xor(a, 2);
    a += __shfl_xor(a, 4); a += __shfl_xor(a, 8);
    acc[vc] = a;
  }
  if (pl == 0) {
    #pragma unroll
    for (int vc = 0; vc < 32; vc++)
      lc[((size_t)b * 16 + kc) * 32 + vc] = acc[vc];
  }
}

// ---------------------------------------------------------------------------
// K4: pos conv (im2col MFMA) + content fold + q-contraction + bn2 + relu
// grid (16 tiles of 16x16 px, 32 b); E padded to 16x256 (dy,dx -> 16 each)
// pos[k][px] accumulated in MFMA acc (M=16 k-ch, N=16 px, K=256 taps)
// ---------------------------------------------------------------------------
__global__ __launch_bounds__(256) void k4_pos(
    const unsigned short* __restrict__ qo, const unsigned short* __restrict__ vo,
    const float* __restrict__ lc, const float* __restrict__ emb,
    const float* __restrict__ g2, const float* __restrict__ b2,
    const float* __restrict__ m2, const float* __restrict__ v2,
    unsigned short* __restrict__ g) {
  __shared__ unsigned short vh[30784];      // [32 vc][30 yy][32 xx] + slack, zeroed
  __shared__ float lcs[512];
  __shared__ float sc[128], bi[128];
  const int t = threadIdx.x, b = blockIdx.y, tile = blockIdx.x;
  const int ty = (tile >> 2) * 16, tx = (tile & 3) * 16;
  const int lane = t & 63, wv = t >> 6;
  const int px = lane & 15, kg = lane >> 4;
  if (t < 128) { float s = g2[t] * rsqrtf(v2[t] + EPS); sc[t] = s; bi[t] = b2[t] - m2[t] * s; }
  for (int e = t; e < 512; e += 256) lcs[e] = lc[b * 512 + e];
  {
    unsigned* vz = reinterpret_cast<unsigned*>(vh);
    for (int i = t; i < 15392; i += 256) vz[i] = 0;
  }
  // E fragments in registers: A[m=k-ch (lane&15)][kd], kd = 32c + 8kg + j
  bf16x8 ef[8];
  #pragma unroll
  for (int c = 0; c < 8; c++) {
    #pragma unroll
    for (int j = 0; j < 8; j++) {
      const int kd = 32 * c + 8 * kg + j;
      const int dy = kd >> 4, dx = kd & 15;
      float val = (dy < 15 && dx < 15) ? emb[(px * 15 + dy) * 15 + dx] : 0.f;
      ef[c][j] = (short)f2bf(val);
    }
  }
  __syncthreads();
  // stage v halo (zero-padded borders already zeroed)
  const unsigned short* vb = vo + (size_t)b * 32 * 4096;
  for (int r = t; r < 960; r += 256) {
    const int vc = r / 30, yy = r % 30;
    const int gy = ty + yy - 7;
    if (gy >= 0 && gy < 64) {
      const int x0 = tx - 7;
      const int xs = x0 < 0 ? -x0 : 0;
      const int xe = (x0 + 30 > 64) ? (64 - x0) : 30;
      const unsigned short* src = vb + vc * 4096 + gy * 64 + x0;
      unsigned short* dst = vh + (vc * 30 + yy) * 32;
      for (int xx = xs; xx < xe; xx++) dst[xx] = src[xx];
    }
  }
  __syncthreads();
  const unsigned short* qb = qo + (size_t)b * 64 * 4096;
  unsigned short* gb = g + (size_t)b * 128 * 4096;
  const int dyk = kg >> 1, dx0 = (kg & 1) * 8;
  for (int nbi = 0; nbi < 4; nbi++) {
    const int nb = wv * 4 + nbi;                 // tile row handled by this wave
    const int pixg = (ty + nb) * 64 + tx + px;
    float qr[4][4];
    #pragma unroll
    for (int hh = 0; hh < 4; hh++)
      #pragma unroll
      for (int r = 0; r < 4; r++)
        qr[hh][r] = bf2f(qb[(size_t)(hh * 16 + 4 * kg + r) * 4096 + pixg]);
    auto emit = [&](const f32x4& a, int vc2) {
      float s0 = 0, s1 = 0, s2 = 0, s3 = 0;
      #pragma unroll
      for (int r = 0; r < 4; r++) {
        const float p = a[r] + lcs[(4 * kg + r) * 32 + vc2];  // + content lambda
        s0 = fmaf(qr[0][r], p, s0); s1 = fmaf(qr[1][r], p, s1);
        s2 = fmaf(qr[2][r], p, s2); s3 = fmaf(qr[3][r], p, s3);
      }
      s0 += __shfl_xor(s0, 16); s0 += __shfl_xor(s0, 32);
      s1 += __shfl_xor(s1, 16); s1 += __shfl_xor(s1, 32);
      s2 += __shfl_xor(s2, 16); s2 += __shfl_xor(s2, 32);
      s3 += __shfl_xor(s3, 16); s3 += __shfl_xor(s3, 32);
      const float ssel = kg == 0 ? s0 : kg == 1 ? s1 : kg == 2 ? s2 : s3;
      const int ch = kg * 32 + vc2;              // out channel = head*32 + vc
      float val = fmaxf(fmaf(ssel, sc[ch], bi[ch]), 0.f);
      gb[(size_t)ch * 4096 + pixg] = f2bf(val);
    };
    for (int vc = 0; vc < 32; vc += 2) {
      f32x4 a0 = {}, a1 = {};
      #pragma unroll
      for (int c = 0; c < 8; c++) {
        const int yy = nb + 2 * c + dyk;
        const unsigned short* p0 = &vh[(vc * 30 + yy) * 32 + px + dx0];
        const unsigned short* p1 = p0 + 960;     // vc+1
        bf16x8 b0, b1;
        #pragma unroll
        for (int j = 0; j < 8; j++) { b0[j] = (short)p0[j]; b1[j] = (short)p1[j]; }
        a0 = __builtin_amdgcn_mfma_f32_16x16x32_bf16(ef[c], b0, a0, 0, 0, 0);
        a1 = __builtin_amdgcn_mfma_f32_16x16x32_bf16(ef[c], b1, a1, 0, 0, 0);
      }
      emit(a0, vc);
      emit(a1, vc + 1);
    }
  }
}

// ---------------------------------------------------------------------------
// K5: out = relu(bn3(conv3(g)) + x)   M=512, K=128; BM=256, BN=64
// ---------------------------------------------------------------------------
__global__ __launch_bounds__(256) void k5_conv3(
    const unsigned short* __restrict__ g, const float* __restrict__ w3,
    const float* __restrict__ g3, const float* __restrict__ b3,
    const float* __restrict__ m3, const float* __restrict__ v3,
    const float* __restrict__ x, float* __restrict__ out) {
  __shared__ unsigned short As[256 * 72];
  __shared__ unsigned short Bs[64 * 72];
  __shared__ float sc[256], bi[256];
  const int t = threadIdx.x;
  const int n0 = blockIdx.x * 64, m0 = blockIdx.y * 256, b = blockIdx.z;
  {
    const int ch = m0 + t;
    float s = g3[ch] * rsqrtf(v3[ch] + EPS);
    sc[t] = s; bi[t] = b3[ch] - m3[ch] * s;
  }
  const int lane = t & 63, wv = t >> 6;
  const int wm = (wv >> 1) * 128, wn = (wv & 1) * 32;
  const int l15 = lane & 15, kg = lane >> 4;
  f32x4 acc[8][2] = {};
  const unsigned short* gbuf = g + (size_t)b * 128 * 4096;
  for (int kt = 0; kt < 128; kt += 64) {
    __syncthreads();
    { // stage A = w3 tile: one row per thread, 64 k
      const float* src = w3 + (size_t)(m0 + t) * 128 + kt;
      unsigned short* dst = As + t * 72;
      #pragma unroll
      for (int i = 0; i < 16; i++)
        cvt4(reinterpret_cast<const float4*>(src)[i], dst + 4 * i);
    }
    { // stage B^T from g
      const int c = t >> 2, p0 = (t & 3) * 16;
      const unsigned short* src = gbuf + (size_t)(kt + c) * 4096 + n0 + p0;
      #pragma unroll
      for (int i = 0; i < 4; i++) {
        ushort4 u = reinterpret_cast<const ushort4*>(src)[i];
        const int p = p0 + 4 * i;
        Bs[(p + 0) * 72 + c] = u.x; Bs[(p + 1) * 72 + c] = u.y;
        Bs[(p + 2) * 72 + c] = u.z; Bs[(p + 3) * 72 + c] = u.w;
      }
    }
    __syncthreads();
    #pragma unroll
    for (int kk = 0; kk < 64; kk += 32) {
      bf16x8 bfr[2];
      #pragma unroll
      for (int nf = 0; nf < 2; nf++)
        bfr[nf] = *reinterpret_cast<const bf16x8*>(
            &Bs[(wn + nf * 16 + l15) * 72 + kk + 8 * kg]);
      #pragma unroll
      for (int mf = 0; mf < 8; mf++) {
        bf16x8 af = *reinterpret_cast<const bf16x8*>(
            &As[(wm + mf * 16 + l15) * 72 + kk + 8 * kg]);
        #pragma unroll
        for (int nf = 0; nf < 2; nf++)
          acc[mf][nf] = __builtin_amdgcn_mfma_f32_16x16x32_bf16(
              af, bfr[nf], acc[mf][nf], 0, 0, 0);
      }
    }
  }
  const float* xb = x + ((size_t)b * 512 + m0) * 4096;
  float* ob = out + ((size_t)b * 512 + m0) * 4096;
  #pragma unroll
  for (int mf = 0; mf < 8; mf++)
    #pragma unroll
    for (int nf = 0; nf < 2; nf++) {
      const int px = n0 + wn + nf * 16 + l15;
      #pragma unroll
      for (int r = 0; r < 4; r++) {
        const int ch = wm + mf * 16 + 4 * kg + r;   // local channel (0..255)
        float val = fmaf(acc[mf][nf][r], sc[ch], bi[ch]) + xb[(size_t)ch * 4096 + px];
        ob[(size_t)ch * 4096 + px] = fmaxf(val, 0.f);
      }
    }
}

// ---------------------------------------------------------------------------
extern "C" void kernel_launch(void* const* d_in, const int* in_sizes, int n_in,
                              void* d_out, int out_size, void* d_ws, size_t ws_size,
                              hipStream_t stream) {
  (void)in_sizes; (void)n_in; (void)out_size; (void)ws_size;
  const float* x   = (const float*)d_in[0];
  const float* w1  = (const float*)d_in[1];
  const float* g1  = (const float*)d_in[2];
  const float* b1  = (const float*)d_in[3];
  const float* m1  = (const float*)d_in[4];
  const float* v1  = (const float*)d_in[5];
  const float* qw  = (const float*)d_in[6];
  const float* gq  = (const float*)d_in[7];
  const float* bq  = (const float*)d_in[8];
  const float* mq  = (const float*)d_in[9];
  const float* vq  = (const float*)d_in[10];
  const float* kw  = (const float*)d_in[11];
  const float* vw  = (const float*)d_in[12];
  const float* gv  = (const float*)d_in[13];
  const float* bv  = (const float*)d_in[14];
  const float* mv  = (const float*)d_in[15];
  const float* vv  = (const float*)d_in[16];
  const float* emb = (const float*)d_in[17];
  const float* g2  = (const float*)d_in[18];
  const float* b2  = (const float*)d_in[19];
  const float* m2  = (const float*)d_in[20];
  const float* v2  = (const float*)d_in[21];
  const float* w3  = (const float*)d_in[22];
  const float* g3  = (const float*)d_in[23];
  const float* b3  = (const float*)d_in[24];
  const float* m3  = (const float*)d_in[25];
  const float* v3  = (const float*)d_in[26];
  float* out = (float*)d_out;

  char* ws = (char*)d_ws;
  unsigned short* hbuf = (unsigned short*)(ws);             // 33,554,432 B (reused for g)
  unsigned short* qbuf = (unsigned short*)(ws + 33554432);  // 16,777,216 B
  unsigned short* kbuf = (unsigned short*)(ws + 50331648);  //  4,194,304 B
  unsigned short* vbuf = (unsigned short*)(ws + 54525952);  //  8,388,608 B
  float*          lcb  = (float*)        (ws + 62914560);   //     65,536 B

  k1_conv1<<<dim3(64, 32), 256, 0, stream>>>(x, w1, g1, b1, m1, v1, hbuf);
  k2_qkv<<<dim3(64, 32), 256, 0, stream>>>(hbuf, qw, kw, vw, gq, bq, mq, vq,
                                           gv, bv, mv, vv, qbuf, kbuf, vbuf);
  k3_lambda<<<dim3(32), 256, 0, stream>>>(kbuf, vbuf, lcb);
  k4_pos<<<dim3(16, 32), 256, 0, stream>>>(qbuf, vbuf, lcb, emb, g2, b2, m2, v2, hbuf);
  k5_conv3<<<dim3(64, 2, 32), 256, 0, stream>>>(hbuf, w3, g3, b3, m3, v3, x, out);
}

// Round 2
// 1041.235 us; speedup vs baseline: 1.1573x; 1.1573x over previous
//
#include <hip/hip_runtime.h>

#define EPS 1e-5f

typedef __attribute__((ext_vector_type(8))) short bf16x8;
typedef __attribute__((ext_vector_type(8))) unsigned short u16x8;
typedef __attribute__((ext_vector_type(4))) float f32x4;

__device__ __forceinline__ unsigned short f2bf(float f) {
  union { float f; unsigned u; } c; c.f = f;
  unsigned u = c.u;
  u += 0x7FFFu + ((u >> 16) & 1u);   // round-to-nearest-even
  return (unsigned short)(u >> 16);
}
__device__ __forceinline__ float bf2f(unsigned short h) {
  union { unsigned u; float f; } c; c.u = (unsigned)h << 16;
  return c.f;
}
__device__ __forceinline__ void gl_lds16(const void* gsrc, void* lds) {
  __builtin_amdgcn_global_load_lds(
      (const __attribute__((address_space(1))) unsigned*)gsrc,
      (__attribute__((address_space(3))) unsigned*)lds, 16, 0, 0);
}

// ---------------------------------------------------------------------------
// k0: convert w1 (128x512) and w3 (512x128) to bf16 in ws
// ---------------------------------------------------------------------------
__global__ __launch_bounds__(256) void k0_prep(
    const float* __restrict__ w1, const float* __restrict__ w3,
    unsigned short* __restrict__ w1bf, unsigned short* __restrict__ w3bf) {
  const int i = (blockIdx.x * 256 + threadIdx.x) * 4;   // 128 blocks: 131072 elems
  const float* src = i < 65536 ? w1 + i : w3 + (i - 65536);
  unsigned short* dst = i < 65536 ? w1bf + i : w3bf + (i - 65536);
  float4 f = *reinterpret_cast<const float4*>(src);
  ushort4 o; o.x = f2bf(f.x); o.y = f2bf(f.y); o.z = f2bf(f.z); o.w = f2bf(f.w);
  *reinterpret_cast<ushort4*>(dst) = o;
}

// ---------------------------------------------------------------------------
// K1: h = relu(bn1(conv1(x)))   per batch GEMM M=128(ch), N=4096(px), K=512
// BM=128, BN=128, BK=64; waves 2x2, wave tile 64ch x 64px
// As: w1bf via global_load_lds, linear [128][64], chunk swizzle key (ch&7)
// Bs: x transposed, padded [128][72], chunk swizzle key ((px>>2)&7)
// ---------------------------------------------------------------------------
__global__ __launch_bounds__(256) void k1_conv1(
    const float* __restrict__ x, const unsigned short* __restrict__ w1bf,
    const float* __restrict__ g1, const float* __restrict__ b1,
    const float* __restrict__ m1, const float* __restrict__ v1,
    unsigned short* __restrict__ h) {
  __shared__ unsigned short As[128 * 64];
  __shared__ unsigned short Bs[128 * 72];
  __shared__ float sc[128], bi[128];
  const int t = threadIdx.x;
  const int b = blockIdx.y;
  const int n0 = blockIdx.x * 128;
  if (t < 128) {
    float s = g1[t] * rsqrtf(v1[t] + EPS);
    sc[t] = s; bi[t] = b1[t] - m1[t] * s;
  }
  const int lane = t & 63, wv = t >> 6;
  const int wm = (wv >> 1) * 64, wn = (wv & 1) * 64;
  const int l15 = lane & 15, kg = lane >> 4;
  const int sl = lane & 7, rr = lane >> 3;
  f32x4 acc[4][4] = {};
  const float* xb = x + (size_t)b * 512 * 4096;
  const int cB = t >> 2, psB = (t & 3) * 8;      // Bs staging mapping
  for (int kt = 0; kt < 512; kt += 64) {
    __syncthreads();
    { // stage As: 4 waves x 4 insts x 8 rows
      const int r0 = wv * 32;
      #pragma unroll
      for (int j = 0; j < 4; j++) {
        const int row = r0 + j * 8 + rr;
        const int chunk = sl ^ (row & 7);
        gl_lds16(w1bf + row * 512 + kt + chunk * 8, &As[(r0 + j * 8) * 64]);
      }
    }
    { // stage Bs: transpose x[ch][px] -> Bs[px][ch], swizzled
      const float* src = xb + (size_t)(kt + cB) * 4096 + n0 + psB;
      #pragma unroll
      for (int j = 0; j < 4; j++) {
        float4 f0 = reinterpret_cast<const float4*>(src + 32 * j)[0];
        float4 f1 = reinterpret_cast<const float4*>(src + 32 * j)[1];
        float vals[8] = {f0.x, f0.y, f0.z, f0.w, f1.x, f1.y, f1.z, f1.w};
        #pragma unroll
        for (int e = 0; e < 8; e++) {
          const int px = psB + 32 * j + e;
          Bs[px * 72 + (((cB >> 3) ^ ((px >> 2) & 7)) << 3) + (cB & 7)] = f2bf(vals[e]);
        }
      }
    }
    __syncthreads();
    #pragma unroll
    for (int kk = 0; kk < 64; kk += 32) {
      const int c16 = kg + (kk >> 3);
      bf16x8 af[4], bf[4];
      #pragma unroll
      for (int mf = 0; mf < 4; mf++) {
        const int ch = wm + mf * 16 + l15;
        af[mf] = *reinterpret_cast<const bf16x8*>(&As[ch * 64 + ((c16 ^ (ch & 7)) << 3)]);
      }
      #pragma unroll
      for (int nf = 0; nf < 4; nf++) {
        const int px = wn + nf * 16 + l15;
        bf[nf] = *reinterpret_cast<const bf16x8*>(
            &Bs[px * 72 + ((c16 ^ ((px >> 2) & 7)) << 3)]);
      }
      #pragma unroll
      for (int mf = 0; mf < 4; mf++)
        #pragma unroll
        for (int nf = 0; nf < 4; nf++)
          acc[mf][nf] = __builtin_amdgcn_mfma_f32_16x16x32_bf16(
              af[mf], bf[nf], acc[mf][nf], 0, 0, 0);
    }
  }
  unsigned short* hb = h + (size_t)b * 128 * 4096;
  #pragma unroll
  for (int mf = 0; mf < 4; mf++)
    #pragma unroll
    for (int nf = 0; nf < 4; nf++) {
      const int px = n0 + wn + nf * 16 + l15;
      #pragma unroll
      for (int r = 0; r < 4; r++) {
        const int ch = wm + mf * 16 + 4 * kg + r;
        float val = fmaxf(fmaf(acc[mf][nf][r], sc[ch], bi[ch]), 0.f);
        hb[(size_t)ch * 4096 + px] = f2bf(val);
      }
    }
}

// ---------------------------------------------------------------------------
// K2: qkv = Wqkv * h ; epilogue: bn(q), softmax16(k), bn(v)   (unchanged)
// ---------------------------------------------------------------------------
__global__ __launch_bounds__(256) void k2_qkv(
    const unsigned short* __restrict__ h,
    const float* __restrict__ qw, const float* __restrict__ kw,
    const float* __restrict__ vw,
    const float* __restrict__ gq, const float* __restrict__ bq,
    const float* __restrict__ mq, const float* __restrict__ vq,
    const float* __restrict__ gv, const float* __restrict__ bv,
    const float* __restrict__ mv, const float* __restrict__ vv,
    unsigned short* __restrict__ qo, unsigned short* __restrict__ ko,
    unsigned short* __restrict__ vo) {
  __shared__ unsigned short As[112 * 72];
  __shared__ unsigned short Bs[64 * 72];
  __shared__ float sc[112], bi[112];
  const int t = threadIdx.x, b = blockIdx.y, n0 = blockIdx.x * 64;
  if (t < 112) {
    float s, bb;
    if (t < 64)      { s = gq[t] * rsqrtf(vq[t] + EPS); bb = bq[t] - mq[t] * s; }
    else if (t < 80) { s = 1.f; bb = 0.f; }
    else { int c = t - 80; s = gv[c] * rsqrtf(vv[c] + EPS); bb = bv[c] - mv[c] * s; }
    sc[t] = s; bi[t] = bb;
  }
  const int lane = t & 63, wv = t >> 6;
  const int l15 = lane & 15, kg = lane >> 4;
  f32x4 acc[7] = {};
  const unsigned short* hb = h + (size_t)b * 128 * 4096;
  for (int kt = 0; kt < 128; kt += 64) {
    __syncthreads();
    for (int e = t; e < 112 * 64; e += 256) {
      const int row = e >> 6, kk2 = e & 63, gk = kt + kk2;
      float val = row < 64 ? qw[row * 128 + gk]
                : row < 80 ? kw[(row - 64) * 128 + gk]
                           : vw[(row - 80) * 128 + gk];
      As[row * 72 + kk2] = f2bf(val);
    }
    {
      const int c = t >> 2, p0 = (t & 3) * 16;
      const unsigned short* src = hb + (size_t)(kt + c) * 4096 + n0 + p0;
      #pragma unroll
      for (int i = 0; i < 4; i++) {
        ushort4 u = reinterpret_cast<const ushort4*>(src)[i];
        const int p = p0 + 4 * i;
        Bs[(p + 0) * 72 + c] = u.x; Bs[(p + 1) * 72 + c] = u.y;
        Bs[(p + 2) * 72 + c] = u.z; Bs[(p + 3) * 72 + c] = u.w;
      }
    }
    __syncthreads();
    #pragma unroll
    for (int kk = 0; kk < 64; kk += 32) {
      bf16x8 bfr = *reinterpret_cast<const bf16x8*>(
          &Bs[(wv * 16 + l15) * 72 + kk + 8 * kg]);
      #pragma unroll
      for (int mf = 0; mf < 7; mf++) {
        bf16x8 af = *reinterpret_cast<const bf16x8*>(
            &As[(mf * 16 + l15) * 72 + kk + 8 * kg]);
        acc[mf] = __builtin_amdgcn_mfma_f32_16x16x32_bf16(af, bfr, acc[mf], 0, 0, 0);
      }
    }
  }
  const int px = n0 + wv * 16 + l15;
  float e0[4];
  float mx = -1e30f;
  #pragma unroll
  for (int r = 0; r < 4; r++) mx = fmaxf(mx, acc[4][r]);
  mx = fmaxf(mx, __shfl_xor(mx, 16));
  mx = fmaxf(mx, __shfl_xor(mx, 32));
  float s = 0.f;
  #pragma unroll
  for (int r = 0; r < 4; r++) { e0[r] = expf(acc[4][r] - mx); s += e0[r]; }
  s += __shfl_xor(s, 16); s += __shfl_xor(s, 32);
  const float inv = 1.f / s;
  #pragma unroll
  for (int mf = 0; mf < 7; mf++) {
    #pragma unroll
    for (int r = 0; r < 4; r++) {
      const int row = mf * 16 + 4 * kg + r;
      if (mf == 4) {
        ko[((size_t)b * 16 + (row - 64)) * 4096 + px] = f2bf(e0[r] * inv);
      } else {
        float val = fmaf(acc[mf][r], sc[row], bi[row]);
        if (row < 64) qo[((size_t)b * 64 + row) * 4096 + px] = f2bf(val);
        else          vo[((size_t)b * 32 + (row - 80)) * 4096 + px] = f2bf(val);
      }
    }
  }
}

// ---------------------------------------------------------------------------
// K3: content_lambda  (unchanged)
// ---------------------------------------------------------------------------
__global__ __launch_bounds__(256) void k3_lambda(
    const unsigned short* __restrict__ ko, const unsigned short* __restrict__ vo,
    float* __restrict__ lc) {
  const int t = threadIdx.x, b = blockIdx.x;
  const int kc = t >> 4, pl = t & 15;
  const unsigned short* kb = ko + ((size_t)b * 16 + kc) * 4096;
  const unsigned short* vb = vo + (size_t)b * 32 * 4096;
  float acc[32] = {};
  for (int i = 0; i < 256; i++) {
    const int pix = pl + 16 * i;
    const float kv = bf2f(kb[pix]);
    #pragma unroll
    for (int vc = 0; vc < 32; vc++)
      acc[vc] = fmaf(kv, bf2f(vb[vc * 4096 + pix]), acc[vc]);
  }
  #pragma unroll
  for (int vc = 0; vc < 32; vc++) {
    float a = acc[vc];
    a += __shfl_xor(a, 1); a += __shfl_xor(a, 2);
    a += __shfl_xor(a, 4); a += __shfl_xor(a, 8);
    acc[vc] = a;
  }
  if (pl == 0) {
    #pragma unroll
    for (int vc = 0; vc < 32; vc++)
      lc[((size_t)b * 16 + kc) * 32 + vc] = acc[vc];
  }
}

// ---------------------------------------------------------------------------
// K4: pos conv (im2col MFMA) + content fold + q-contraction + bn2 + relu
// (unchanged)
// ---------------------------------------------------------------------------
__global__ __launch_bounds__(256) void k4_pos(
    const unsigned short* __restrict__ qo, const unsigned short* __restrict__ vo,
    const float* __restrict__ lc, const float* __restrict__ emb,
    const float* __restrict__ g2, const float* __restrict__ b2,
    const float* __restrict__ m2, const float* __restrict__ v2,
    unsigned short* __restrict__ g) {
  __shared__ unsigned short vh[30784];
  __shared__ float lcs[512];
  __shared__ float sc[128], bi[128];
  const int t = threadIdx.x, b = blockIdx.y, tile = blockIdx.x;
  const int ty = (tile >> 2) * 16, tx = (tile & 3) * 16;
  const int lane = t & 63, wv = t >> 6;
  const int px = lane & 15, kg = lane >> 4;
  if (t < 128) { float s = g2[t] * rsqrtf(v2[t] + EPS); sc[t] = s; bi[t] = b2[t] - m2[t] * s; }
  for (int e = t; e < 512; e += 256) lcs[e] = lc[b * 512 + e];
  {
    unsigned* vz = reinterpret_cast<unsigned*>(vh);
    for (int i = t; i < 15392; i += 256) vz[i] = 0;
  }
  bf16x8 ef[8];
  #pragma unroll
  for (int c = 0; c < 8; c++) {
    #pragma unroll
    for (int j = 0; j < 8; j++) {
      const int kd = 32 * c + 8 * kg + j;
      const int dy = kd >> 4, dx = kd & 15;
      float val = (dy < 15 && dx < 15) ? emb[(px * 15 + dy) * 15 + dx] : 0.f;
      ef[c][j] = (short)f2bf(val);
    }
  }
  __syncthreads();
  const unsigned short* vb = vo + (size_t)b * 32 * 4096;
  for (int r = t; r < 960; r += 256) {
    const int vc = r / 30, yy = r % 30;
    const int gy = ty + yy - 7;
    if (gy >= 0 && gy < 64) {
      const int x0 = tx - 7;
      const int xs = x0 < 0 ? -x0 : 0;
      const int xe = (x0 + 30 > 64) ? (64 - x0) : 30;
      const unsigned short* src = vb + vc * 4096 + gy * 64 + x0;
      unsigned short* dst = vh + (vc * 30 + yy) * 32;
      for (int xx = xs; xx < xe; xx++) dst[xx] = src[xx];
    }
  }
  __syncthreads();
  const unsigned short* qb = qo + (size_t)b * 64 * 4096;
  unsigned short* gb = g + (size_t)b * 128 * 4096;
  const int dyk = kg >> 1, dx0 = (kg & 1) * 8;
  for (int nbi = 0; nbi < 4; nbi++) {
    const int nb = wv * 4 + nbi;
    const int pixg = (ty + nb) * 64 + tx + px;
    float qr[4][4];
    #pragma unroll
    for (int hh = 0; hh < 4; hh++)
      #pragma unroll
      for (int r = 0; r < 4; r++)
        qr[hh][r] = bf2f(qb[(size_t)(hh * 16 + 4 * kg + r) * 4096 + pixg]);
    auto emit = [&](const f32x4& a, int vc2) {
      float s0 = 0, s1 = 0, s2 = 0, s3 = 0;
      #pragma unroll
      for (int r = 0; r < 4; r++) {
        const float p = a[r] + lcs[(4 * kg + r) * 32 + vc2];
        s0 = fmaf(qr[0][r], p, s0); s1 = fmaf(qr[1][r], p, s1);
        s2 = fmaf(qr[2][r], p, s2); s3 = fmaf(qr[3][r], p, s3);
      }
      s0 += __shfl_xor(s0, 16); s0 += __shfl_xor(s0, 32);
      s1 += __shfl_xor(s1, 16); s1 += __shfl_xor(s1, 32);
      s2 += __shfl_xor(s2, 16); s2 += __shfl_xor(s2, 32);
      s3 += __shfl_xor(s3, 16); s3 += __shfl_xor(s3, 32);
      const float ssel = kg == 0 ? s0 : kg == 1 ? s1 : kg == 2 ? s2 : s3;
      const int ch = kg * 32 + vc2;
      float val = fmaxf(fmaf(ssel, sc[ch], bi[ch]), 0.f);
      gb[(size_t)ch * 4096 + pixg] = f2bf(val);
    };
    for (int vc = 0; vc < 32; vc += 2) {
      f32x4 a0 = {}, a1 = {};
      #pragma unroll
      for (int c = 0; c < 8; c++) {
        const int yy = nb + 2 * c + dyk;
        const unsigned short* p0 = &vh[(vc * 30 + yy) * 32 + px + dx0];
        const unsigned short* p1 = p0 + 960;
        bf16x8 b0, b1;
        #pragma unroll
        for (int j = 0; j < 8; j++) { b0[j] = (short)p0[j]; b1[j] = (short)p1[j]; }
        a0 = __builtin_amdgcn_mfma_f32_16x16x32_bf16(ef[c], b0, a0, 0, 0, 0);
        a1 = __builtin_amdgcn_mfma_f32_16x16x32_bf16(ef[c], b1, a1, 0, 0, 0);
      }
      emit(a0, vc);
      emit(a1, vc + 1);
    }
  }
}

// ---------------------------------------------------------------------------
// K5: out = relu(bn3(conv3(g)) + x)
// SWAPPED operands: A = g pixels (M=128px), B = w3 (N=128ch), K=128, BK=64
// As: g transposed [128px][72] padded, chunk swizzle key ((px>>2)&7)
// Bs: w3bf via global_load_lds, linear [128][64], chunk swizzle key (ch&7)
// Epilogue: float4 x-read / out-write (D rows = 4 consecutive px)
// ---------------------------------------------------------------------------
__global__ __launch_bounds__(256) void k5_conv3(
    const unsigned short* __restrict__ g, const unsigned short* __restrict__ w3bf,
    const float* __restrict__ g3, const float* __restrict__ b3,
    const float* __restrict__ m3, const float* __restrict__ v3,
    const float* __restrict__ x, float* __restrict__ out) {
  __shared__ unsigned short As[128 * 72];
  __shared__ unsigned short Bs[128 * 64];
  __shared__ float sc[128], bi[128];
  const int t = threadIdx.x;
  const int n0 = blockIdx.x * 128, m0 = blockIdx.y * 128, b = blockIdx.z;
  if (t < 128) {
    const int ch = m0 + t;
    float s = g3[ch] * rsqrtf(v3[ch] + EPS);
    sc[t] = s; bi[t] = b3[ch] - m3[ch] * s;
  }
  const int lane = t & 63, wv = t >> 6;
  const int wpx = (wv >> 1) * 64, wch = (wv & 1) * 64;
  const int l15 = lane & 15, kg = lane >> 4;
  const int sl = lane & 7, rr = lane >> 3;
  f32x4 acc[4][4] = {};
  const unsigned short* gb = g + (size_t)b * 128 * 4096;
  const int cA = t >> 2, psA = (t & 3) * 8;
  for (int kt = 0; kt < 128; kt += 64) {
    __syncthreads();
    { // stage As: transpose g[ch][px] -> As[px][ch-chunk], swizzled
      const unsigned short* src = gb + (size_t)(kt + cA) * 4096 + n0 + psA;
      #pragma unroll
      for (int j = 0; j < 4; j++) {
        u16x8 u = *reinterpret_cast<const u16x8*>(src + 32 * j);
        #pragma unroll
        for (int e = 0; e < 8; e++) {
          const int px = psA + 32 * j + e;
          As[px * 72 + (((cA >> 3) ^ ((px >> 2) & 7)) << 3) + (cA & 7)] = u[e];
        }
      }
    }
    { // stage Bs: w3bf rows (out-ch), global_load_lds
      const int r0 = wv * 32;
      #pragma unroll
      for (int j = 0; j < 4; j++) {
        const int row = r0 + j * 8 + rr;
        const int chunk = sl ^ (row & 7);
        gl_lds16(w3bf + (size_t)(m0 + row) * 128 + kt + chunk * 8,
                 &Bs[(r0 + j * 8) * 64]);
      }
    }
    __syncthreads();
    #pragma unroll
    for (int kk = 0; kk < 64; kk += 32) {
      const int c16 = kg + (kk >> 3);
      bf16x8 af[4], bf[4];
      #pragma unroll
      for (int mf = 0; mf < 4; mf++) {
        const int px = wpx + mf * 16 + l15;
        af[mf] = *reinterpret_cast<const bf16x8*>(
            &As[px * 72 + ((c16 ^ ((px >> 2) & 7)) << 3)]);
      }
      #pragma unroll
      for (int nf = 0; nf < 4; nf++) {
        const int row = wch + nf * 16 + l15;
        bf[nf] = *reinterpret_cast<const bf16x8*>(
            &Bs[row * 64 + ((c16 ^ (row & 7)) << 3)]);
      }
      #pragma unroll
      for (int mf = 0; mf < 4; mf++)
        #pragma unroll
        for (int nf = 0; nf < 4; nf++)
          acc[mf][nf] = __builtin_amdgcn_mfma_f32_16x16x32_bf16(
              af[mf], bf[nf], acc[mf][nf], 0, 0, 0);
    }
  }
  #pragma unroll
  for (int mf = 0; mf < 4; mf++)
    #pragma unroll
    for (int nf = 0; nf < 4; nf++) {
      const int chl = wch + nf * 16 + l15;
      const size_t base = ((size_t)b * 512 + m0 + chl) * 4096 +
                          (n0 + wpx + mf * 16 + 4 * kg);
      float4 xv = *reinterpret_cast<const float4*>(x + base);
      float4 o;
      o.x = fmaxf(fmaf(acc[mf][nf][0], sc[chl], bi[chl]) + xv.x, 0.f);
      o.y = fmaxf(fmaf(acc[mf][nf][1], sc[chl], bi[chl]) + xv.y, 0.f);
      o.z = fmaxf(fmaf(acc[mf][nf][2], sc[chl], bi[chl]) + xv.z, 0.f);
      o.w = fmaxf(fmaf(acc[mf][nf][3], sc[chl], bi[chl]) + xv.w, 0.f);
      *reinterpret_cast<float4*>(out + base) = o;
    }
}

// ---------------------------------------------------------------------------
extern "C" void kernel_launch(void* const* d_in, const int* in_sizes, int n_in,
                              void* d_out, int out_size, void* d_ws, size_t ws_size,
                              hipStream_t stream) {
  (void)in_sizes; (void)n_in; (void)out_size; (void)ws_size;
  const float* x   = (const float*)d_in[0];
  const float* w1  = (const float*)d_in[1];
  const float* g1  = (const float*)d_in[2];
  const float* b1  = (const float*)d_in[3];
  const float* m1  = (const float*)d_in[4];
  const float* v1  = (const float*)d_in[5];
  const float* qw  = (const float*)d_in[6];
  const float* gq  = (const float*)d_in[7];
  const float* bq  = (const float*)d_in[8];
  const float* mq  = (const float*)d_in[9];
  const float* vq  = (const float*)d_in[10];
  const float* kw  = (const float*)d_in[11];
  const float* vw  = (const float*)d_in[12];
  const float* gv  = (const float*)d_in[13];
  const float* bv  = (const float*)d_in[14];
  const float* mv  = (const float*)d_in[15];
  const float* vv  = (const float*)d_in[16];
  const float* emb = (const float*)d_in[17];
  const float* g2  = (const float*)d_in[18];
  const float* b2  = (const float*)d_in[19];
  const float* m2  = (const float*)d_in[20];
  const float* v2  = (const float*)d_in[21];
  const float* w3  = (const float*)d_in[22];
  const float* g3  = (const float*)d_in[23];
  const float* b3  = (const float*)d_in[24];
  const float* m3  = (const float*)d_in[25];
  const float* v3  = (const float*)d_in[26];
  float* out = (float*)d_out;

  char* ws = (char*)d_ws;
  unsigned short* hbuf = (unsigned short*)(ws);             // 33,554,432 B (reused for g)
  unsigned short* qbuf = (unsigned short*)(ws + 33554432);  // 16,777,216 B
  unsigned short* kbuf = (unsigned short*)(ws + 50331648);  //  4,194,304 B
  unsigned short* vbuf = (unsigned short*)(ws + 54525952);  //  8,388,608 B
  float*          lcb  = (float*)        (ws + 62914560);   //     65,536 B
  unsigned short* w1bf = (unsigned short*)(ws + 62980096);  //    131,072 B
  unsigned short* w3bf = (unsigned short*)(ws + 63111168);  //    131,072 B

  k0_prep<<<dim3(128), 256, 0, stream>>>(w1, w3, w1bf, w3bf);
  k1_conv1<<<dim3(32, 32), 256, 0, stream>>>(x, w1bf, g1, b1, m1, v1, hbuf);
  k2_qkv<<<dim3(64, 32), 256, 0, stream>>>(hbuf, qw, kw, vw, gq, bq, mq, vq,
                                           gv, bv, mv, vv, qbuf, kbuf, vbuf);
  k3_lambda<<<dim3(32), 256, 0, stream>>>(kbuf, vbuf, lcb);
  k4_pos<<<dim3(16, 32), 256, 0, stream>>>(qbuf, vbuf, lcb, emb, g2, b2, m2, v2, hbuf);
  k5_conv3<<<dim3(32, 4, 32), 256, 0, stream>>>(hbuf, w3bf, g3, b3, m3, v3, x, out);
}

// Round 4
// 834.894 us; speedup vs baseline: 1.4433x; 1.2471x over previous
//
#include <hip/hip_runtime.h>

#define EPS 1e-5f

typedef __attribute__((ext_vector_type(8))) short bf16x8;
typedef __attribute__((ext_vector_type(8))) unsigned short u16x8;
typedef __attribute__((ext_vector_type(4))) float f32x4;
typedef __attribute__((ext_vector_type(2))) unsigned u32x2;
typedef __attribute__((ext_vector_type(4))) unsigned u32x4;

__device__ __forceinline__ unsigned short f2bf(float f) {
  union { float f; unsigned u; } c; c.f = f;
  unsigned u = c.u;
  u += 0x7FFFu + ((u >> 16) & 1u);   // round-to-nearest-even
  return (unsigned short)(u >> 16);
}
__device__ __forceinline__ float bf2f(unsigned short h) {
  union { unsigned u; float f; } c; c.u = (unsigned)h << 16;
  return c.f;
}
__device__ __forceinline__ void gl_lds16(const void* gsrc, void* lds) {
  __builtin_amdgcn_global_load_lds(
      (const __attribute__((address_space(1))) unsigned*)gsrc,
      (__attribute__((address_space(3))) unsigned*)lds, 16, 0, 0);
}
__device__ __forceinline__ float sel4(int i, float a, float b, float c, float d) {
  float lo = (i & 1) ? b : a;
  float hi = (i & 1) ? d : c;
  return (i & 2) ? hi : lo;
}

// ---------------------------------------------------------------------------
// k0: convert w1 (128x512) and w3 (512x128) to bf16 in ws
// ---------------------------------------------------------------------------
__global__ __launch_bounds__(256) void k0_prep(
    const float* __restrict__ w1, const float* __restrict__ w3,
    unsigned short* __restrict__ w1bf, unsigned short* __restrict__ w3bf) {
  const int i = (blockIdx.x * 256 + threadIdx.x) * 4;
  const float* src = i < 65536 ? w1 + i : w3 + (i - 65536);
  unsigned short* dst = i < 65536 ? w1bf + i : w3bf + (i - 65536);
  float4 f = *reinterpret_cast<const float4*>(src);
  ushort4 o; o.x = f2bf(f.x); o.y = f2bf(f.y); o.z = f2bf(f.z); o.w = f2bf(f.w);
  *reinterpret_cast<ushort4*>(dst) = o;
}

// ---------------------------------------------------------------------------
// K1: h = relu(bn1(conv1(x)))  (unchanged from round 1)
// ---------------------------------------------------------------------------
__global__ __launch_bounds__(256) void k1_conv1(
    const float* __restrict__ x, const unsigned short* __restrict__ w1bf,
    const float* __restrict__ g1, const float* __restrict__ b1,
    const float* __restrict__ m1, const float* __restrict__ v1,
    unsigned short* __restrict__ h) {
  __shared__ unsigned short As[128 * 64];
  __shared__ unsigned short Bs[128 * 72];
  __shared__ float sc[128], bi[128];
  const int t = threadIdx.x;
  const int b = blockIdx.y;
  const int n0 = blockIdx.x * 128;
  if (t < 128) {
    float s = g1[t] * rsqrtf(v1[t] + EPS);
    sc[t] = s; bi[t] = b1[t] - m1[t] * s;
  }
  const int lane = t & 63, wv = t >> 6;
  const int wm = (wv >> 1) * 64, wn = (wv & 1) * 64;
  const int l15 = lane & 15, kg = lane >> 4;
  const int sl = lane & 7, rr = lane >> 3;
  f32x4 acc[4][4] = {};
  const float* xb = x + (size_t)b * 512 * 4096;
  const int cB = t >> 2, psB = (t & 3) * 8;
  for (int kt = 0; kt < 512; kt += 64) {
    __syncthreads();
    {
      const int r0 = wv * 32;
      #pragma unroll
      for (int j = 0; j < 4; j++) {
        const int row = r0 + j * 8 + rr;
        const int chunk = sl ^ (row & 7);
        gl_lds16(w1bf + row * 512 + kt + chunk * 8, &As[(r0 + j * 8) * 64]);
      }
    }
    {
      const float* src = xb + (size_t)(kt + cB) * 4096 + n0 + psB;
      #pragma unroll
      for (int j = 0; j < 4; j++) {
        float4 f0 = reinterpret_cast<const float4*>(src + 32 * j)[0];
        float4 f1 = reinterpret_cast<const float4*>(src + 32 * j)[1];
        float vals[8] = {f0.x, f0.y, f0.z, f0.w, f1.x, f1.y, f1.z, f1.w};
        #pragma unroll
        for (int e = 0; e < 8; e++) {
          const int px = psB + 32 * j + e;
          Bs[px * 72 + (((cB >> 3) ^ ((px >> 2) & 7)) << 3) + (cB & 7)] = f2bf(vals[e]);
        }
      }
    }
    __syncthreads();
    #pragma unroll
    for (int kk = 0; kk < 64; kk += 32) {
      const int c16 = kg + (kk >> 3);
      bf16x8 af[4], bf[4];
      #pragma unroll
      for (int mf = 0; mf < 4; mf++) {
        const int ch = wm + mf * 16 + l15;
        af[mf] = *reinterpret_cast<const bf16x8*>(&As[ch * 64 + ((c16 ^ (ch & 7)) << 3)]);
      }
      #pragma unroll
      for (int nf = 0; nf < 4; nf++) {
        const int px = wn + nf * 16 + l15;
        bf[nf] = *reinterpret_cast<const bf16x8*>(
            &Bs[px * 72 + ((c16 ^ ((px >> 2) & 7)) << 3)]);
      }
      #pragma unroll
      for (int mf = 0; mf < 4; mf++)
        #pragma unroll
        for (int nf = 0; nf < 4; nf++)
          acc[mf][nf] = __builtin_amdgcn_mfma_f32_16x16x32_bf16(
              af[mf], bf[nf], acc[mf][nf], 0, 0, 0);
    }
  }
  unsigned short* hb = h + (size_t)b * 128 * 4096;
  #pragma unroll
  for (int mf = 0; mf < 4; mf++)
    #pragma unroll
    for (int nf = 0; nf < 4; nf++) {
      const int px = n0 + wn + nf * 16 + l15;
      #pragma unroll
      for (int r = 0; r < 4; r++) {
        const int ch = wm + mf * 16 + 4 * kg + r;
        float val = fmaxf(fmaf(acc[mf][nf][r], sc[ch], bi[ch]), 0.f);
        hb[(size_t)ch * 4096 + px] = f2bf(val);
      }
    }
}

// ---------------------------------------------------------------------------
// K2: qkv = Wqkv * h ; epilogue: bn(q), softmax16(k), bn(v)   (unchanged)
// ---------------------------------------------------------------------------
__global__ __launch_bounds__(256) void k2_qkv(
    const unsigned short* __restrict__ h,
    const float* __restrict__ qw, const float* __restrict__ kw,
    const float* __restrict__ vw,
    const float* __restrict__ gq, const float* __restrict__ bq,
    const float* __restrict__ mq, const float* __restrict__ vq,
    const float* __restrict__ gv, const float* __restrict__ bv,
    const float* __restrict__ mv, const float* __restrict__ vv,
    unsigned short* __restrict__ qo, unsigned short* __restrict__ ko,
    unsigned short* __restrict__ vo) {
  __shared__ unsigned short As[112 * 72];
  __shared__ unsigned short Bs[64 * 72];
  __shared__ float sc[112], bi[112];
  const int t = threadIdx.x, b = blockIdx.y, n0 = blockIdx.x * 64;
  if (t < 112) {
    float s, bb;
    if (t < 64)      { s = gq[t] * rsqrtf(vq[t] + EPS); bb = bq[t] - mq[t] * s; }
    else if (t < 80) { s = 1.f; bb = 0.f; }
    else { int c = t - 80; s = gv[c] * rsqrtf(vv[c] + EPS); bb = bv[c] - mv[c] * s; }
    sc[t] = s; bi[t] = bb;
  }
  const int lane = t & 63, wv = t >> 6;
  const int l15 = lane & 15, kg = lane >> 4;
  f32x4 acc[7] = {};
  const unsigned short* hb = h + (size_t)b * 128 * 4096;
  for (int kt = 0; kt < 128; kt += 64) {
    __syncthreads();
    for (int e = t; e < 112 * 64; e += 256) {
      const int row = e >> 6, kk2 = e & 63, gk = kt + kk2;
      float val = row < 64 ? qw[row * 128 + gk]
                : row < 80 ? kw[(row - 64) * 128 + gk]
                           : vw[(row - 80) * 128 + gk];
      As[row * 72 + kk2] = f2bf(val);
    }
    {
      const int c = t >> 2, p0 = (t & 3) * 16;
      const unsigned short* src = hb + (size_t)(kt + c) * 4096 + n0 + p0;
      #pragma unroll
      for (int i = 0; i < 4; i++) {
        ushort4 u = reinterpret_cast<const ushort4*>(src)[i];
        const int p = p0 + 4 * i;
        Bs[(p + 0) * 72 + c] = u.x; Bs[(p + 1) * 72 + c] = u.y;
        Bs[(p + 2) * 72 + c] = u.z; Bs[(p + 3) * 72 + c] = u.w;
      }
    }
    __syncthreads();
    #pragma unroll
    for (int kk = 0; kk < 64; kk += 32) {
      bf16x8 bfr = *reinterpret_cast<const bf16x8*>(
          &Bs[(wv * 16 + l15) * 72 + kk + 8 * kg]);
      #pragma unroll
      for (int mf = 0; mf < 7; mf++) {
        bf16x8 af = *reinterpret_cast<const bf16x8*>(
            &As[(mf * 16 + l15) * 72 + kk + 8 * kg]);
        acc[mf] = __builtin_amdgcn_mfma_f32_16x16x32_bf16(af, bfr, acc[mf], 0, 0, 0);
      }
    }
  }
  const int px = n0 + wv * 16 + l15;
  float e0[4];
  float mx = -1e30f;
  #pragma unroll
  for (int r = 0; r < 4; r++) mx = fmaxf(mx, acc[4][r]);
  mx = fmaxf(mx, __shfl_xor(mx, 16));
  mx = fmaxf(mx, __shfl_xor(mx, 32));
  float s = 0.f;
  #pragma unroll
  for (int r = 0; r < 4; r++) { e0[r] = expf(acc[4][r] - mx); s += e0[r]; }
  s += __shfl_xor(s, 16); s += __shfl_xor(s, 32);
  const float inv = 1.f / s;
  #pragma unroll
  for (int mf = 0; mf < 7; mf++) {
    #pragma unroll
    for (int r = 0; r < 4; r++) {
      const int row = mf * 16 + 4 * kg + r;
      if (mf == 4) {
        ko[((size_t)b * 16 + (row - 64)) * 4096 + px] = f2bf(e0[r] * inv);
      } else {
        float val = fmaf(acc[mf][r], sc[row], bi[row]);
        if (row < 64) qo[((size_t)b * 64 + row) * 4096 + px] = f2bf(val);
        else          vo[((size_t)b * 32 + (row - 80)) * 4096 + px] = f2bf(val);
      }
    }
  }
}

// ---------------------------------------------------------------------------
// K3: content_lambda  (unchanged)
// ---------------------------------------------------------------------------
__global__ __launch_bounds__(256) void k3_lambda(
    const unsigned short* __restrict__ ko, const unsigned short* __restrict__ vo,
    float* __restrict__ lc) {
  const int t = threadIdx.x, b = blockIdx.x;
  const int kc = t >> 4, pl = t & 15;
  const unsigned short* kb = ko + ((size_t)b * 16 + kc) * 4096;
  const unsigned short* vb = vo + (size_t)b * 32 * 4096;
  float acc[32] = {};
  for (int i = 0; i < 256; i++) {
    const int pix = pl + 16 * i;
    const float kv = bf2f(kb[pix]);
    #pragma unroll
    for (int vc = 0; vc < 32; vc++)
      acc[vc] = fmaf(kv, bf2f(vb[vc * 4096 + pix]), acc[vc]);
  }
  #pragma unroll
  for (int vc = 0; vc < 32; vc++) {
    float a = acc[vc];
    a += __shfl_xor(a, 1); a += __shfl_xor(a, 2);
    a += __shfl_xor(a, 4); a += __shfl_xor(a, 8);
    acc[vc] = a;
  }
  if (pl == 0) {
    #pragma unroll
    for (int vc = 0; vc < 32; vc++)
      lc[((size_t)b * 16 + kc) * 32 + vc] = acc[vc];
  }
}

// ---------------------------------------------------------------------------
// K4: pos conv via ds_read_b64_tr_b16 im2col MFMA
//   vh layout: [32 vc][2 planes][32 rows][16 cols] u16  (row pitch = 32B,
//   matching tr-read's fixed 4x(+32B) per-lane stride)
//   tap->k-slot map: dy = 4*(m&3) + (j&3), dx = kg + 4*(j>>2) + 8*(m>>2)
//   per (y,vc): 16 tr-reads -> 8 MFMAs (K padded 256 vs 225 useful)
//   epilogue: +lambda_c, q-contraction, 3-shfl kg-butterfly, bn2+relu
// ---------------------------------------------------------------------------
__global__ __launch_bounds__(256) void k4_pos(
    const unsigned short* __restrict__ qo, const unsigned short* __restrict__ vo,
    const float* __restrict__ lc, const float* __restrict__ emb,
    const float* __restrict__ g2, const float* __restrict__ b2,
    const float* __restrict__ m2, const float* __restrict__ v2,
    unsigned short* __restrict__ g) {
  __shared__ unsigned short vh[32 * 2 * 32 * 16];   // 65536 B
  __shared__ float lcs2[512];                        // [vc][kch]
  __shared__ float sc[128], bi[128];
  const int t = threadIdx.x, b = blockIdx.y, tile = blockIdx.x;
  const int ty = (tile >> 2) * 16, tx = (tile & 3) * 16;
  const int lane = t & 63, wv = t >> 6;
  const int px = lane & 15, kg = lane >> 4;
  if (t < 128) { float s = g2[t] * rsqrtf(v2[t] + EPS); sc[t] = s; bi[t] = b2[t] - m2[t] * s; }
  for (int e = t; e < 512; e += 256) {
    const int vc = e >> 4, kch = e & 15;
    lcs2[e] = lc[b * 512 + kch * 32 + vc];
  }
  { // zero vh (covers halo borders + pad rows/planes)
    u32x4 z = {0, 0, 0, 0};
    for (int i = t; i < 4096; i += 256)
      *reinterpret_cast<u32x4*>(&vh[i * 8]) = z;
  }
  // E fragments: af[m][j] = E[kch=px][dy][dx] per tap->k-slot map
  bf16x8 af[8];
  #pragma unroll
  for (int m = 0; m < 8; m++) {
    #pragma unroll
    for (int j = 0; j < 8; j++) {
      const int dy = 4 * (m & 3) + (j & 3);
      const int dx = kg + 4 * (j >> 2) + 8 * (m >> 2);
      float val = (dy < 15 && dx < 15) ? emb[(px * 15 + dy) * 15 + dx] : 0.f;
      af[m][j] = (short)f2bf(val);
    }
  }
  __syncthreads();
  // stage halo: vh[vc][p][row][c] = v[vc][ty+row-7][tx-8+16p+c], zero OOB
  const unsigned short* vb = vo + (size_t)b * 32 * 4096;
  for (int task = t; task < 32 * 2 * 30 * 2; task += 256) {
    const int half = task & 1, row = (task >> 1) % 30, pv = (task >> 1) / 30;
    const int p = pv & 1, vc = pv >> 1;
    const int gy = ty + row - 7;
    const int gx = tx - 8 + p * 16 + half * 8;
    if (gy >= 0 && gy < 64 && gx >= 0 && gx <= 56) {
      u16x8 u = *reinterpret_cast<const u16x8*>(vb + vc * 4096 + gy * 64 + gx);
      *reinterpret_cast<u16x8*>(&vh[((vc * 2 + p) * 32 + row) * 16 + half * 8]) = u;
    }
  }
  __syncthreads();

  // per-lane tr column offsets: col = px + kg + 1 + 4c, c in [0,4)
  unsigned fo[4];
  #pragma unroll
  for (int c = 0; c < 4; c++) {
    const int col = px + kg + 1 + 4 * c;
    fo[c] = (unsigned)((col >> 4) * 1024 + (col & 15) * 2);
  }
  const unsigned vhOFF = (unsigned)(size_t)(&vh[0]);
  const unsigned short* qb = qo + (size_t)b * 64 * 4096;
  unsigned short* gb = g + (size_t)b * 128 * 4096;

#define TRRD(dst, areg, IMM) \
  asm volatile("ds_read_b64_tr_b16 %0, %1 offset:" IMM : "=v"(dst) : "v"(areg))

  for (int yi = 0; yi < 4; yi++) {
    const int ylocal = wv * 4 + yi;
    const int pixg = (ty + ylocal) * 64 + tx + px;
    // q for this pixel (held in regs across all vc)
    float qr[4][4];
    #pragma unroll
    for (int hh = 0; hh < 4; hh++)
      #pragma unroll
      for (int r = 0; r < 4; r++)
        qr[hh][r] = bf2f(qb[(size_t)(hh * 16 + 4 * kg + r) * 4096 + pixg]);
    const unsigned rowb = vhOFF + (unsigned)(ylocal * 32);
    for (int vc = 0; vc < 32; vc++) {
      const unsigned vb0 = rowb + (unsigned)(vc * 2048);
      const unsigned a0 = vb0 + fo[0], a1 = vb0 + fo[1];
      const unsigned a2 = vb0 + fo[2], a3 = vb0 + fo[3];
      u32x2 tr0[8], tr1[8];
      TRRD(tr0[0], a0, "0");   TRRD(tr1[0], a1, "0");
      TRRD(tr0[1], a0, "128"); TRRD(tr1[1], a1, "128");
      TRRD(tr0[2], a0, "256"); TRRD(tr1[2], a1, "256");
      TRRD(tr0[3], a0, "384"); TRRD(tr1[3], a1, "384");
      TRRD(tr0[4], a2, "0");   TRRD(tr1[4], a3, "0");
      TRRD(tr0[5], a2, "128"); TRRD(tr1[5], a3, "128");
      TRRD(tr0[6], a2, "256"); TRRD(tr1[6], a3, "256");
      TRRD(tr0[7], a2, "384"); TRRD(tr1[7], a3, "384");
      float4 lcv = *reinterpret_cast<const float4*>(&lcs2[vc * 16 + kg * 4]);
      asm volatile("s_waitcnt lgkmcnt(0)" ::: "memory");
      __builtin_amdgcn_sched_barrier(0);
      f32x4 acc = {0.f, 0.f, 0.f, 0.f};
      #pragma unroll
      for (int m = 0; m < 8; m++) {
        u32x4 u;
        u[0] = tr0[m][0]; u[1] = tr0[m][1];
        u[2] = tr1[m][0]; u[3] = tr1[m][1];
        acc = __builtin_amdgcn_mfma_f32_16x16x32_bf16(
            af[m], __builtin_bit_cast(bf16x8, u), acc, 0, 0, 0);
      }
      // epilogue: fold lambda_c, contract with q, butterfly over kg, bn2+relu
      float p0 = acc[0] + lcv.x, p1 = acc[1] + lcv.y;
      float p2 = acc[2] + lcv.z, p3 = acc[3] + lcv.w;
      float s0 = qr[0][0] * p0; s0 = fmaf(qr[0][1], p1, s0);
      s0 = fmaf(qr[0][2], p2, s0); s0 = fmaf(qr[0][3], p3, s0);
      float s1 = qr[1][0] * p0; s1 = fmaf(qr[1][1], p1, s1);
      s1 = fmaf(qr[1][2], p2, s1); s1 = fmaf(qr[1][3], p3, s1);
      float s2 = qr[2][0] * p0; s2 = fmaf(qr[2][1], p1, s2);
      s2 = fmaf(qr[2][2], p2, s2); s2 = fmaf(qr[2][3], p3, s2);
      float s3 = qr[3][0] * p0; s3 = fmaf(qr[3][1], p1, s3);
      s3 = fmaf(qr[3][2], p2, s3); s3 = fmaf(qr[3][3], p3, s3);
      // lane kg keeps head kg: S = sum over kg' of s_{kg}^{(kg')}
      float skg = sel4(kg,     s0, s1, s2, s3);
      float sx1 = sel4(kg ^ 1, s0, s1, s2, s3);
      float sx2 = sel4(kg ^ 2, s0, s1, s2, s3);
      float sx3 = sel4(kg ^ 3, s0, s1, s2, s3);
      float tt  = skg + __shfl_xor(sx1, 16);
      float tt2 = sx2 + __shfl_xor(sx3, 16);
      float S   = tt + __shfl_xor(tt2, 32);
      const int ch = kg * 32 + vc;
      float val = fmaxf(fmaf(S, sc[ch], bi[ch]), 0.f);
      gb[(size_t)ch * 4096 + pixg] = f2bf(val);
    }
  }
#undef TRRD
}

// ---------------------------------------------------------------------------
// K5: out = relu(bn3(conv3(g)) + x)   (unchanged from round 1)
// ---------------------------------------------------------------------------
__global__ __launch_bounds__(256) void k5_conv3(
    const unsigned short* __restrict__ g, const unsigned short* __restrict__ w3bf,
    const float* __restrict__ g3, const float* __restrict__ b3,
    const float* __restrict__ m3, const float* __restrict__ v3,
    const float* __restrict__ x, float* __restrict__ out) {
  __shared__ unsigned short As[128 * 72];
  __shared__ unsigned short Bs[128 * 64];
  __shared__ float sc[128], bi[128];
  const int t = threadIdx.x;
  const int n0 = blockIdx.x * 128, m0 = blockIdx.y * 128, b = blockIdx.z;
  if (t < 128) {
    const int ch = m0 + t;
    float s = g3[ch] * rsqrtf(v3[ch] + EPS);
    sc[t] = s; bi[t] = b3[ch] - m3[ch] * s;
  }
  const int lane = t & 63, wv = t >> 6;
  const int wpx = (wv >> 1) * 64, wch = (wv & 1) * 64;
  const int l15 = lane & 15, kg = lane >> 4;
  const int sl = lane & 7, rr = lane >> 3;
  f32x4 acc[4][4] = {};
  const unsigned short* gb = g + (size_t)b * 128 * 4096;
  const int cA = t >> 2, psA = (t & 3) * 8;
  for (int kt = 0; kt < 128; kt += 64) {
    __syncthreads();
    {
      const unsigned short* src = gb + (size_t)(kt + cA) * 4096 + n0 + psA;
      #pragma unroll
      for (int j = 0; j < 4; j++) {
        u16x8 u = *reinterpret_cast<const u16x8*>(src + 32 * j);
        #pragma unroll
        for (int e = 0; e < 8; e++) {
          const int px = psA + 32 * j + e;
          As[px * 72 + (((cA >> 3) ^ ((px >> 2) & 7)) << 3) + (cA & 7)] = u[e];
        }
      }
    }
    {
      const int r0 = wv * 32;
      #pragma unroll
      for (int j = 0; j < 4; j++) {
        const int row = r0 + j * 8 + rr;
        const int chunk = sl ^ (row & 7);
        gl_lds16(w3bf + (size_t)(m0 + row) * 128 + kt + chunk * 8,
                 &Bs[(r0 + j * 8) * 64]);
      }
    }
    __syncthreads();
    #pragma unroll
    for (int kk = 0; kk < 64; kk += 32) {
      const int c16 = kg + (kk >> 3);
      bf16x8 af[4], bf[4];
      #pragma unroll
      for (int mf = 0; mf < 4; mf++) {
        const int px = wpx + mf * 16 + l15;
        af[mf] = *reinterpret_cast<const bf16x8*>(
            &As[px * 72 + ((c16 ^ ((px >> 2) & 7)) << 3)]);
      }
      #pragma unroll
      for (int nf = 0; nf < 4; nf++) {
        const int row = wch + nf * 16 + l15;
        bf[nf] = *reinterpret_cast<const bf16x8*>(
            &Bs[row * 64 + ((c16 ^ (row & 7)) << 3)]);
      }
      #pragma unroll
      for (int mf = 0; mf < 4; mf++)
        #pragma unroll
        for (int nf = 0; nf < 4; nf++)
          acc[mf][nf] = __builtin_amdgcn_mfma_f32_16x16x32_bf16(
              af[mf], bf[nf], acc[mf][nf], 0, 0, 0);
    }
  }
  #pragma unroll
  for (int mf = 0; mf < 4; mf++)
    #pragma unroll
    for (int nf = 0; nf < 4; nf++) {
      const int chl = wch + nf * 16 + l15;
      const size_t base = ((size_t)b * 512 + m0 + chl) * 4096 +
                          (n0 + wpx + mf * 16 + 4 * kg);
      float4 xv = *reinterpret_cast<const float4*>(x + base);
      float4 o;
      o.x = fmaxf(fmaf(acc[mf][nf][0], sc[chl], bi[chl]) + xv.x, 0.f);
      o.y = fmaxf(fmaf(acc[mf][nf][1], sc[chl], bi[chl]) + xv.y, 0.f);
      o.z = fmaxf(fmaf(acc[mf][nf][2], sc[chl], bi[chl]) + xv.z, 0.f);
      o.w = fmaxf(fmaf(acc[mf][nf][3], sc[chl], bi[chl]) + xv.w, 0.f);
      *reinterpret_cast<float4*>(out + base) = o;
    }
}

// ---------------------------------------------------------------------------
extern "C" void kernel_launch(void* const* d_in, const int* in_sizes, int n_in,
                              void* d_out, int out_size, void* d_ws, size_t ws_size,
                              hipStream_t stream) {
  (void)in_sizes; (void)n_in; (void)out_size; (void)ws_size;
  const float* x   = (const float*)d_in[0];
  const float* w1  = (const float*)d_in[1];
  const float* g1  = (const float*)d_in[2];
  const float* b1  = (const float*)d_in[3];
  const float* m1  = (const float*)d_in[4];
  const float* v1  = (const float*)d_in[5];
  const float* qw  = (const float*)d_in[6];
  const float* gq  = (const float*)d_in[7];
  const float* bq  = (const float*)d_in[8];
  const float* mq  = (const float*)d_in[9];
  const float* vq  = (const float*)d_in[10];
  const float* kw  = (const float*)d_in[11];
  const float* vw  = (const float*)d_in[12];
  const float* gv  = (const float*)d_in[13];
  const float* bv  = (const float*)d_in[14];
  const float* mv  = (const float*)d_in[15];
  const float* vv  = (const float*)d_in[16];
  const float* emb = (const float*)d_in[17];
  const float* g2  = (const float*)d_in[18];
  const float* b2  = (const float*)d_in[19];
  const float* m2  = (const float*)d_in[20];
  const float* v2  = (const float*)d_in[21];
  const float* w3  = (const float*)d_in[22];
  const float* g3  = (const float*)d_in[23];
  const float* b3  = (const float*)d_in[24];
  const float* m3  = (const float*)d_in[25];
  const float* v3  = (const float*)d_in[26];
  float* out = (float*)d_out;

  char* ws = (char*)d_ws;
  unsigned short* hbuf = (unsigned short*)(ws);             // 33,554,432 B (reused for g)
  unsigned short* qbuf = (unsigned short*)(ws + 33554432);  // 16,777,216 B
  unsigned short* kbuf = (unsigned short*)(ws + 50331648);  //  4,194,304 B
  unsigned short* vbuf = (unsigned short*)(ws + 54525952);  //  8,388,608 B
  float*          lcb  = (float*)        (ws + 62914560);   //     65,536 B
  unsigned short* w1bf = (unsigned short*)(ws + 62980096);  //    131,072 B
  unsigned short* w3bf = (unsigned short*)(ws + 63111168);  //    131,072 B

  k0_prep<<<dim3(128), 256, 0, stream>>>(w1, w3, w1bf, w3bf);
  k1_conv1<<<dim3(32, 32), 256, 0, stream>>>(x, w1bf, g1, b1, m1, v1, hbuf);
  k2_qkv<<<dim3(64, 32), 256, 0, stream>>>(hbuf, qw, kw, vw, gq, bq, mq, vq,
                                           gv, bv, mv, vv, qbuf, kbuf, vbuf);
  k3_lambda<<<dim3(32), 256, 0, stream>>>(kbuf, vbuf, lcb);
  k4_pos<<<dim3(16, 32), 256, 0, stream>>>(qbuf, vbuf, lcb, emb, g2, b2, m2, v2, hbuf);
  k5_conv3<<<dim3(32, 4, 32), 256, 0, stream>>>(hbuf, w3bf, g3, b3, m3, v3, x, out);
}